// Round 3
// baseline (98.096 us; speedup 1.0000x reference)
//
#include <hip/hip_runtime.h>

// ModalitySpecificLocalSelfAttention — MI355X. Device dtype is UNKNOWN
// (f32 per reference vs bf16 per harness hints), so we detect it at runtime:
// f32 buffers have uniform mantissa bits in even-index u16 words (~1/256 hit
// bf16-exponent==0xFF); real bf16 N(0,1) data never does. All inputs are then
// normalized into a canonical bf16 workspace and one pipeline runs either way.

typedef short short8 __attribute__((ext_vector_type(8)));
typedef float f32x4 __attribute__((ext_vector_type(4)));

#define HW_PIX 16384   // H*W
#define CH 128
#define WIMG 128

// canonical workspace layout, in 16-bit units
#define X_OFF    0            // x  [c][p], 2,097,152
#define W_OFF    2097152      // w_q1,w_q2,w_k1,w_k2,w_v (16384 ea), w_o (32768)
#define SB_OFF   2211840      // 1536 f32 (3072 shorts): s/b per 128, see order below
#define TQ_OFF   2214912      // q slot [p][c]
#define TK_OFF   4312064      // k slot [p][c]
#define V_OFF    6409216      // v slot [p][c]
#define FLAG_OFF 8506368      // int: 1 = inputs are f32

static __device__ __forceinline__ float bf2f(unsigned short u) {
    union { unsigned int i; float f; } c; c.i = ((unsigned int)u) << 16; return c.f;
}
static __device__ __forceinline__ unsigned short f2bf(float f) {
    union { unsigned int i; float f; } c; c.f = f;
    unsigned int x = c.i;
    return (unsigned short)((x + 0x7fffu + ((x >> 16) & 1u)) >> 16);  // RNE
}

// ---- dtype detection: scan even-index u16 words of x ----
__global__ __launch_bounds__(256)
void detect_k(const unsigned short* __restrict__ x16, int* __restrict__ flagp)
{
    const int tid = threadIdx.x;
    int cnt = 0;
    for (int i = tid; i < 16384; i += 256) {
        unsigned short w = x16[2 * i];          // low half if f32
        if (((w >> 7) & 0xFF) == 0xFF) cnt++;   // bf16-view exponent all-ones
    }
    __shared__ int total;
    if (tid == 0) total = 0;
    __syncthreads();
    atomicAdd(&total, cnt);
    __syncthreads();
    if (tid == 0) *flagp = (total >= 4) ? 1 : 0;
}

// ---- normalize all inputs into canonical ws ----
struct CvtArgs {
    const void* src[7];   // x, w_q1, w_q2, w_k1, w_k2, w_v, w_o
    const void* sb[12];   // s_q1,b_q1,s_q2,b_q2,s_k1,b_k1,s_k2,b_k2,s_v,b_v,s_o,b_o
};

__global__ __launch_bounds__(256)
void cvt_k(CvtArgs a, short* __restrict__ ws, const int* __restrict__ flagp)
{
    const bool isf32 = (*flagp != 0);
    const int stride = gridDim.x * blockDim.x;
    for (int u = blockIdx.x * blockDim.x + threadIdx.x; u < 278016; u += stride) {
        if (u < 276480) {                       // 2,211,840 bf16 targets, 8/unit
            const int s0 = u * 8;
            int seg, base;
            if      (s0 < 2097152) { seg = 0; base = 0; }
            else if (s0 < 2113536) { seg = 1; base = 2097152; }
            else if (s0 < 2129920) { seg = 2; base = 2113536; }
            else if (s0 < 2146304) { seg = 3; base = 2129920; }
            else if (s0 < 2162688) { seg = 4; base = 2146304; }
            else if (s0 < 2179072) { seg = 5; base = 2162688; }
            else                   { seg = 6; base = 2179072; }
            const int local = s0 - base;
            short8 outv;
            if (isf32) {
                const float* fp = (const float*)a.src[seg] + local;
                #pragma unroll
                for (int j = 0; j < 8; ++j) outv[j] = (short)f2bf(fp[j]);
            } else {
                outv = *(const short8*)((const short*)a.src[seg] + local);
            }
            *(short8*)(ws + s0) = outv;
        } else {                                // 1536 scale/bias floats
            const int idx = u - 276480;
            const int seg = idx >> 7, j = idx & 127;
            float v = isf32 ? ((const float*)a.sb[seg])[j]
                            : bf2f(((const unsigned short*)a.sb[seg])[j]);
            ((float*)(ws + SB_OFF))[idx] = v;
        }
    }
}

struct ConvSet {
    const short* Ain;     // [p][split] canonical bf16 (vector path), may be null
    const short* W;       // [128][K] canonical bf16
    const float* s;       // [128] f32
    const float* b;       // [128] f32
    short* out;           // [p][128] bf16 (ignored when OUT_CP)
};

// OUT[p][o] = act( s[o] * sum_k A[p][k] * W[o][k] + b[o] )
// A[p][k]: k <  split -> cs.Ain[p*split + k]            (vector 16B loads)
//          k >= split -> A_cp[(k-split)*HW_PIX + p]     ([c][p], scalar loads)
// Block = 256 thr; tile 32 px * 128 och; wave = 16 px * 64 och.
// In-place (out == Ain) safe: __syncthreads() orders block's reads before its
// writes; blocks own disjoint pixel rows.
template<int K, bool RELU, bool OUT_CP>
__global__ __launch_bounds__(256)
void conv1x1_k(const short* __restrict__ A_cp, int split,
               ConvSet c0, ConvSet c1, ConvSet c2,
               void* dout_raw, const int* __restrict__ flagp)
{
    ConvSet cs = (blockIdx.y == 0) ? c0 : ((blockIdx.y == 1) ? c1 : c2);
    const int tid = threadIdx.x;
    const int l   = tid & 63;
    const int wv  = tid >> 6;
    const int l16 = l & 15;
    const int g   = l >> 4;        // k-group within fragment
    const int pg  = wv >> 1;       // pixel half of the block tile
    const int og  = wv & 1;        // out-channel half
    const int p0b = blockIdx.x * 32;
    const int p0w = p0b + pg * 16;
    const int o0  = og * 64;
    const int p_row = p0w + l16;   // A-operand row (pixel) for this lane

    f32x4 acc[4];
    #pragma unroll
    for (int nt = 0; nt < 4; ++nt) { f32x4 z = {0.f, 0.f, 0.f, 0.f}; acc[nt] = z; }

    #pragma unroll
    for (int kk = 0; kk < K / 32; ++kk) {
        const int kbase = kk * 32 + g * 8;
        short8 av;
        if (kk * 32 >= split) {               // scalar path: [c][p] source
            const short* src = A_cp + (kbase - split) * HW_PIX + p_row;
            #pragma unroll
            for (int j = 0; j < 8; ++j) av[j] = src[j * HW_PIX];
        } else {                               // vector path: [p][c] source
            av = *(const short8*)(cs.Ain + p_row * split + kbase);
        }
        #pragma unroll
        for (int nt = 0; nt < 4; ++nt) {
            const int orow = o0 + nt * 16 + l16;   // B col = out channel
            short8 bv = *(const short8*)(cs.W + orow * K + kbase);
            acc[nt] = __builtin_amdgcn_mfma_f32_16x16x32_bf16(av, bv, acc[nt], 0, 0, 0);
        }
    }

    __syncthreads();   // in-place safety: all K-reads done before any write

    if constexpr (!OUT_CP) {
        #pragma unroll
        for (int nt = 0; nt < 4; ++nt) {
            const int o = o0 + nt * 16 + l16;
            const float sf = cs.s[o], bf = cs.b[o];
            #pragma unroll
            for (int i = 0; i < 4; ++i) {
                float vl = acc[nt][i] * sf + bf;
                if (RELU) vl = fmaxf(vl, 0.f);
                const int p = p0w + g * 4 + i;     // D row = pixel
                cs.out[p * CH + o] = (short)f2bf(vl);
            }
        }
    } else {
        // final conv: re-transpose tile through LDS, store [c][p] f32 or bf16
        extern __shared__ short tile[];            // [128 och][40 px] (padded)
        #pragma unroll
        for (int nt = 0; nt < 4; ++nt) {
            const int o = o0 + nt * 16 + l16;
            const float sf = cs.s[o], bf = cs.b[o];
            #pragma unroll
            for (int i = 0; i < 4; ++i) {
                float vl = acc[nt][i] * sf + bf;
                if (RELU) vl = fmaxf(vl, 0.f);
                const int p_loc = pg * 16 + g * 4 + i;
                tile[o * 40 + p_loc] = (short)f2bf(vl);
            }
        }
        __syncthreads();
        const bool isf32 = (*flagp != 0);
        #pragma unroll
        for (int pass = 0; pass < 2; ++pass) {
            const int u = tid + pass * 256;        // 512 units of 8 elems
            const int o_r = u >> 2, q4 = u & 3;
            short8 val = *(const short8*)(&tile[o_r * 40 + q4 * 8]);
            const int doff = o_r * HW_PIX + p0b + q4 * 8;
            if (isf32) {
                f32x4 lo, hi;
                #pragma unroll
                for (int j = 0; j < 4; ++j) {
                    lo[j] = bf2f((unsigned short)val[j]);
                    hi[j] = bf2f((unsigned short)val[4 + j]);
                }
                *(f32x4*)((float*)dout_raw + doff)     = lo;
                *(f32x4*)((float*)dout_raw + doff + 4) = hi;
            } else {
                *(short8*)((short*)dout_raw + doff) = val;
            }
        }
    }
}

// Windowed 7x7 attention over [p][c] bf16 q,k,v. 16 lanes/pixel (8 ch each).
// OOB taps contribute sim = 0 (zero-padded reference), v = 0.
// outp may alias q (each lane reads q only at its own pixel, before writing).
__global__ __launch_bounds__(256)
void attn_k(const short* __restrict__ q, const short* __restrict__ k,
            const short* __restrict__ v, short* __restrict__ outp)
{
    const int tid = threadIdx.x;
    const int lane16 = tid & 15;
    const int p = blockIdx.x * 16 + (tid >> 4);
    const int h = p >> 7, w = p & 127;
    const int cbase = lane16 * 8;

    float qf[8];
    {
        short8 qv = *(const short8*)(q + p * CH + cbase);
        #pragma unroll
        for (int j = 0; j < 8; ++j) qf[j] = bf2f((unsigned short)qv[j]);
    }

    float e[49];
    #pragma unroll
    for (int off = 0; off < 49; ++off) {
        const int di = off / 7 - 3, dj = off % 7 - 3;
        const int hh = h + di, ww = w + dj;
        const bool valid = ((unsigned)hh < 128u) && ((unsigned)ww < 128u);
        float t = 0.f;
        if (valid) {
            const int pk = p + di * WIMG + dj;
            short8 kv = *(const short8*)(k + pk * CH + cbase);
            #pragma unroll
            for (int j = 0; j < 8; ++j) t += qf[j] * bf2f((unsigned short)kv[j]);
        }
        t += __shfl_xor(t, 1, 16);
        t += __shfl_xor(t, 2, 16);
        t += __shfl_xor(t, 4, 16);
        t += __shfl_xor(t, 8, 16);
        e[off] = valid ? t : 0.0f;
    }

    float m = e[0];
    #pragma unroll
    for (int off = 1; off < 49; ++off) m = fmaxf(m, e[off]);
    float Z = 0.f;
    #pragma unroll
    for (int off = 0; off < 49; ++off) { float ex = __expf(e[off] - m); e[off] = ex; Z += ex; }
    const float rz = 1.0f / Z;

    float of[8] = {0.f, 0.f, 0.f, 0.f, 0.f, 0.f, 0.f, 0.f};
    #pragma unroll
    for (int off = 0; off < 49; ++off) {
        const int di = off / 7 - 3, dj = off % 7 - 3;
        const int hh = h + di, ww = w + dj;
        if (((unsigned)hh < 128u) && ((unsigned)ww < 128u)) {
            const int pk = p + di * WIMG + dj;
            short8 vv = *(const short8*)(v + pk * CH + cbase);
            #pragma unroll
            for (int j = 0; j < 8; ++j) of[j] += e[off] * bf2f((unsigned short)vv[j]);
        }
    }
    short8 ov;
    #pragma unroll
    for (int j = 0; j < 8; ++j) ov[j] = (short)f2bf(of[j] * rz);
    *(short8*)(outp + p * CH + cbase) = ov;
}

extern "C" void kernel_launch(void* const* d_in, const int* in_sizes, int n_in,
                              void* d_out, int out_size, void* d_ws, size_t ws_size,
                              hipStream_t stream)
{
    short* ws = (short*)d_ws;
    int* flagp = (int*)(ws + FLAG_OFF);

    short* xc  = ws + X_OFF;
    short* Wq1 = ws + W_OFF;
    short* Wq2 = Wq1 + 16384;
    short* Wk1 = Wq2 + 16384;
    short* Wk2 = Wk1 + 16384;
    short* Wv  = Wk2 + 16384;
    short* Wo  = Wv + 16384;
    float* sb  = (float*)(ws + SB_OFF);
    short* tq1 = ws + TQ_OFF;
    short* tk1 = ws + TK_OFF;
    short* vbf = ws + V_OFF;
    short* att = tq1;               // attention output aliases the q slot

    // 1. detect dtype
    detect_k<<<dim3(1), dim3(256), 0, stream>>>((const unsigned short*)d_in[0], flagp);

    // 2. normalize inputs into canonical ws
    CvtArgs ca;
    ca.src[0] = d_in[0];                                  // x
    ca.src[1] = d_in[1];  ca.src[2] = d_in[4];            // w_q1, w_q2
    ca.src[3] = d_in[7];  ca.src[4] = d_in[10];           // w_k1, w_k2
    ca.src[5] = d_in[13]; ca.src[6] = d_in[16];           // w_v,  w_o
    ca.sb[0] = d_in[2];  ca.sb[1] = d_in[3];              // s_q1, b_q1
    ca.sb[2] = d_in[5];  ca.sb[3] = d_in[6];              // s_q2, b_q2
    ca.sb[4] = d_in[8];  ca.sb[5] = d_in[9];              // s_k1, b_k1
    ca.sb[6] = d_in[11]; ca.sb[7] = d_in[12];             // s_k2, b_k2
    ca.sb[8] = d_in[14]; ca.sb[9] = d_in[15];             // s_v,  b_v
    ca.sb[10] = d_in[17]; ca.sb[11] = d_in[18];           // s_o,  b_o
    cvt_k<<<dim3(512), dim3(256), 0, stream>>>(ca, ws, flagp);

    ConvSet dummy = {nullptr, nullptr, nullptr, nullptr, nullptr};
    dim3 blk(256);

    // 3. stage 1: xc[c][p] -> tq1/tk1/v in [p][c]
    {
        ConvSet a = {nullptr, Wq1, sb + 0 * 128, sb + 1 * 128, tq1};
        ConvSet b = {nullptr, Wk1, sb + 4 * 128, sb + 5 * 128, tk1};
        ConvSet c = {nullptr, Wv,  sb + 8 * 128, sb + 9 * 128, vbf};
        conv1x1_k<128, true, false><<<dim3(512, 3), blk, 0, stream>>>(
            xc, 0, a, b, c, nullptr, flagp);
    }
    // 4. stage 2: q2 over tq1, k2 over tk1, in place
    {
        ConvSet a = {tq1, Wq2, sb + 2 * 128, sb + 3 * 128, tq1};
        ConvSet b = {tk1, Wk2, sb + 6 * 128, sb + 7 * 128, tk1};
        conv1x1_k<128, true, false><<<dim3(512, 2), blk, 0, stream>>>(
            nullptr, 128, a, b, dummy, nullptr, flagp);
    }
    // 5. attention (writes att == tq1 in place)
    attn_k<<<dim3(1024), blk, 0, stream>>>(tq1, tk1, vbf, att);
    // 6. final conv: A = concat(att [p][c] k<128, xc [c][p] k>=128) -> d_out [c][p]
    {
        ConvSet a = {att, Wo, sb + 10 * 128, sb + 11 * 128, nullptr};
        conv1x1_k<256, false, true><<<dim3(512, 1), blk, 128 * 40 * 2, stream>>>(
            xc, 128, a, dummy, dummy, d_out, flagp);
    }
}

// Round 4
// 79.319 us; speedup vs baseline: 1.2367x; 1.2367x over previous
//
#include <hip/hip_runtime.h>

// ModalitySpecificLocalSelfAttention — MI355X. Inputs/outputs are f32
// (established round 3: bf16 interpretation NaN'd, f32 path passed).
// Internals: bf16 MFMA GEMMs over [pixel][channel] tiles.
// 4 dispatches: cvt(weights) -> fused qkv (conv1+conv2+v) -> attn -> final.

typedef short short8 __attribute__((ext_vector_type(8)));
typedef float f32x4 __attribute__((ext_vector_type(4)));

#define HW_PIX 16384   // H*W
#define CH 128

// ws layout in 16-bit units
#define WQ1_OFF 0
#define WQ2_OFF 16384
#define WK1_OFF 32768
#define WK2_OFF 49152
#define WV_OFF  65536
#define WO_OFF  81920          // 128x256
#define SB_OFF  114688         // 1536 f32 (3072 shorts)
#define TQ_OFF  131072         // q slot [p][c] bf16; attn writes back here
#define TK_OFF  (TQ_OFF + 2097152)
#define TV_OFF  (TK_OFF + 2097152)

static __device__ __forceinline__ float bf2f(unsigned short u) {
    union { unsigned int i; float f; } c; c.i = ((unsigned int)u) << 16; return c.f;
}
static __device__ __forceinline__ unsigned short f2bf(float f) {
    union { unsigned int i; float f; } c; c.f = f;
    unsigned int x = c.i;
    return (unsigned short)((x + 0x7fffu + ((x >> 16) & 1u)) >> 16);  // RNE
}

// ---- weights + scale/bias f32 -> canonical bf16/f32 ws ----
struct CvtArgs { const float* w[6]; const float* sb[12]; };

__global__ __launch_bounds__(256)
void cvt_k(CvtArgs a, short* __restrict__ ws)
{
    const int u = blockIdx.x * 256 + threadIdx.x;   // 62 blocks = 15872 units
    if (u < 14336) {                                 // 114688 weight elems
        const int s0 = u * 8;
        const int seg = (s0 < 81920) ? (s0 >> 14) : 5;
        const int base = (seg < 5) ? (seg << 14) : 81920;
        const float* fp = a.w[seg] + (s0 - base);
        short8 o;
        #pragma unroll
        for (int j = 0; j < 8; ++j) o[j] = (short)f2bf(fp[j]);
        *(short8*)(ws + s0) = o;
    } else if (u < 15872) {                          // 1536 scale/bias floats
        const int idx = u - 14336;
        ((float*)(ws + SB_OFF))[idx] = a.sb[idx >> 7][idx & 127];
    }
}

// ---- shared GEMM pieces (16x16x32 bf16 MFMA; wave = 16 px x 64 och) ----
__device__ __forceinline__ void gemm_frags(const short8 af[4], const short* __restrict__ W,
                                           int o0, int l16, int g, f32x4 acc[4])
{
    #pragma unroll
    for (int kk = 0; kk < 4; ++kk) {
        #pragma unroll
        for (int nt = 0; nt < 4; ++nt) {
            short8 bv = *(const short8*)(W + (o0 + nt * 16 + l16) * 128 + kk * 32 + g * 8);
            acc[nt] = __builtin_amdgcn_mfma_f32_16x16x32_bf16(af[kk], bv, acc[nt], 0, 0, 0);
        }
    }
}

__device__ __forceinline__ void epi_to_lds(const f32x4 acc[4], const float* s, const float* b,
                                           short* tile, int pg, int g, int l16, int o0)
{
    #pragma unroll
    for (int nt = 0; nt < 4; ++nt) {
        const int o = o0 + nt * 16 + l16;
        const float sf = s[o], bf = b[o];
        #pragma unroll
        for (int i = 0; i < 4; ++i) {
            const float vl = fmaxf(acc[nt][i] * sf + bf, 0.f);
            tile[(pg * 16 + g * 4 + i) * 136 + o] = (short)f2bf(vl);
        }
    }
}

__device__ __forceinline__ void epi_to_glob(const f32x4 acc[4], const float* s, const float* b,
                                            short* out, int p0w, int g, int l16, int o0)
{
    #pragma unroll
    for (int nt = 0; nt < 4; ++nt) {
        const int o = o0 + nt * 16 + l16;
        const float sf = s[o], bf = b[o];
        #pragma unroll
        for (int i = 0; i < 4; ++i) {
            const float vl = fmaxf(acc[nt][i] * sf + bf, 0.f);   // q2/k2/v all ReLU
            out[(p0w + g * 4 + i) * CH + o] = (short)f2bf(vl);
        }
    }
}

// ---- fused q=conv2(conv1(x)), k=conv2(conv1(x)), v=conv(x) ----
__global__ __launch_bounds__(256)
void qkv_k(const float* __restrict__ x, short* __restrict__ ws)
{
    const float* sb = (const float*)(ws + SB_OFF);
    const int tid = threadIdx.x;
    const int l16 = tid & 15;
    const int g   = (tid & 63) >> 4;
    const int wv  = tid >> 6;
    const int pg  = wv >> 1, og = wv & 1;
    const int p0b = blockIdx.x * 32;
    const int p0w = p0b + pg * 16;
    const int o0  = og * 64;
    const int p_row = p0w + l16;

    __shared__ short tileQ[32 * 136];
    __shared__ short tileK[32 * 136];

    // x A-fragments (f32 [c][p] -> bf16), loaded once, reused for q1/k1/v
    short8 xa[4];
    #pragma unroll
    for (int kk = 0; kk < 4; ++kk) {
        const float* src = x + (kk * 32 + g * 8) * HW_PIX + p_row;
        #pragma unroll
        for (int j = 0; j < 8; ++j) xa[kk][j] = (short)f2bf(src[j * HW_PIX]);
    }

    f32x4 acc[4];
    const f32x4 z = {0.f, 0.f, 0.f, 0.f};

    // q1 -> LDS
    #pragma unroll
    for (int nt = 0; nt < 4; ++nt) acc[nt] = z;
    gemm_frags(xa, ws + WQ1_OFF, o0, l16, g, acc);
    epi_to_lds(acc, sb + 0 * 128, sb + 1 * 128, tileQ, pg, g, l16, o0);

    // k1 -> LDS
    #pragma unroll
    for (int nt = 0; nt < 4; ++nt) acc[nt] = z;
    gemm_frags(xa, ws + WK1_OFF, o0, l16, g, acc);
    epi_to_lds(acc, sb + 4 * 128, sb + 5 * 128, tileK, pg, g, l16, o0);

    // v -> global
    #pragma unroll
    for (int nt = 0; nt < 4; ++nt) acc[nt] = z;
    gemm_frags(xa, ws + WV_OFF, o0, l16, g, acc);
    epi_to_glob(acc, sb + 8 * 128, sb + 9 * 128, ws + TV_OFF, p0w, g, l16, o0);

    __syncthreads();

    // q2 over LDS tileQ -> global q
    short8 lf[4];
    const short* rowQ = tileQ + (pg * 16 + l16) * 136;
    #pragma unroll
    for (int kk = 0; kk < 4; ++kk) lf[kk] = *(const short8*)(rowQ + kk * 32 + g * 8);
    #pragma unroll
    for (int nt = 0; nt < 4; ++nt) acc[nt] = z;
    gemm_frags(lf, ws + WQ2_OFF, o0, l16, g, acc);
    epi_to_glob(acc, sb + 2 * 128, sb + 3 * 128, ws + TQ_OFF, p0w, g, l16, o0);

    // k2 over LDS tileK -> global k
    const short* rowK = tileK + (pg * 16 + l16) * 136;
    #pragma unroll
    for (int kk = 0; kk < 4; ++kk) lf[kk] = *(const short8*)(rowK + kk * 32 + g * 8);
    #pragma unroll
    for (int nt = 0; nt < 4; ++nt) acc[nt] = z;
    gemm_frags(lf, ws + WK2_OFF, o0, l16, g, acc);
    epi_to_glob(acc, sb + 6 * 128, sb + 7 * 128, ws + TK_OFF, p0w, g, l16, o0);
}

// ---- 7x7 windowed attention: 8 lanes/px, 16 ch/lane; writes back to q slot ----
__global__ __launch_bounds__(256)
void attn_k(short* __restrict__ ws)
{
    const short* q = ws + TQ_OFF;
    const short* k = ws + TK_OFF;
    const short* v = ws + TV_OFF;
    short* outp = ws + TQ_OFF;       // alias: q read only at own px, before write

    const int tid = threadIdx.x;
    const int lane8 = tid & 7;
    const int p = blockIdx.x * 32 + (tid >> 3);
    const int h = p >> 7, w = p & 127;
    const int cb = lane8 * 16;

    float qf[16];
    {
        short8 a = *(const short8*)(q + p * CH + cb);
        short8 b = *(const short8*)(q + p * CH + cb + 8);
        #pragma unroll
        for (int j = 0; j < 8; ++j) { qf[j] = bf2f((unsigned short)a[j]); qf[8 + j] = bf2f((unsigned short)b[j]); }
    }

    float e[49];
    #pragma unroll
    for (int off = 0; off < 49; ++off) {
        const int di = off / 7 - 3, dj = off % 7 - 3;
        const int hh = h + di, ww = w + dj;
        const bool valid = ((unsigned)hh < 128u) && ((unsigned)ww < 128u);
        float t = 0.f;
        if (valid) {
            const short* kr = k + (p + di * 128 + dj) * CH + cb;
            short8 a = *(const short8*)kr;
            short8 b = *(const short8*)(kr + 8);
            #pragma unroll
            for (int j = 0; j < 8; ++j) {
                t += qf[j] * bf2f((unsigned short)a[j]);
                t += qf[8 + j] * bf2f((unsigned short)b[j]);
            }
        }
        t += __shfl_xor(t, 1, 8);
        t += __shfl_xor(t, 2, 8);
        t += __shfl_xor(t, 4, 8);
        e[off] = valid ? t : 0.f;
    }

    float m = e[0];
    #pragma unroll
    for (int off = 1; off < 49; ++off) m = fmaxf(m, e[off]);
    float Z = 0.f;
    #pragma unroll
    for (int off = 0; off < 49; ++off) { const float ex = __expf(e[off] - m); e[off] = ex; Z += ex; }
    const float rz = 1.0f / Z;

    float of[16];
    #pragma unroll
    for (int j = 0; j < 16; ++j) of[j] = 0.f;
    #pragma unroll
    for (int off = 0; off < 49; ++off) {
        const int di = off / 7 - 3, dj = off % 7 - 3;
        const int hh = h + di, ww = w + dj;
        if (((unsigned)hh < 128u) && ((unsigned)ww < 128u)) {
            const short* vr = v + (p + di * 128 + dj) * CH + cb;
            short8 a = *(const short8*)vr;
            short8 b = *(const short8*)(vr + 8);
            const float ev = e[off];
            #pragma unroll
            for (int j = 0; j < 8; ++j) {
                of[j]     += ev * bf2f((unsigned short)a[j]);
                of[8 + j] += ev * bf2f((unsigned short)b[j]);
            }
        }
    }
    short8 oa, ob;
    #pragma unroll
    for (int j = 0; j < 8; ++j) { oa[j] = (short)f2bf(of[j] * rz); ob[j] = (short)f2bf(of[8 + j] * rz); }
    *(short8*)(outp + p * CH + cb) = oa;
    *(short8*)(outp + p * CH + cb + 8) = ob;
}

// ---- final conv: concat(att, x) [K=256] -> d_out f32 [c][p] ----
__global__ __launch_bounds__(256)
void final_k(const float* __restrict__ x, const short* __restrict__ ws, float* __restrict__ out)
{
    const short* att = ws + TQ_OFF;
    const short* Wo  = ws + WO_OFF;
    const float* sb  = (const float*)(ws + SB_OFF);
    const float* s   = sb + 10 * 128;
    const float* b   = sb + 11 * 128;

    const int tid = threadIdx.x;
    const int l16 = tid & 15;
    const int g   = (tid & 63) >> 4;
    const int wv  = tid >> 6;
    const int pg  = wv >> 1, og = wv & 1;
    const int p0b = blockIdx.x * 32;
    const int p0w = p0b + pg * 16;
    const int o0  = og * 64;
    const int p_row = p0w + l16;

    f32x4 acc[4];
    const f32x4 z = {0.f, 0.f, 0.f, 0.f};
    #pragma unroll
    for (int nt = 0; nt < 4; ++nt) acc[nt] = z;

    #pragma unroll
    for (int kk = 0; kk < 8; ++kk) {
        const int kbase = kk * 32 + g * 8;
        short8 av;
        if (kk < 4) {                              // attention half (bf16 [p][c])
            av = *(const short8*)(att + p_row * CH + kbase);
        } else {                                   // x half (f32 [c][p])
            const float* src = x + (kbase - 128) * HW_PIX + p_row;
            #pragma unroll
            for (int j = 0; j < 8; ++j) av[j] = (short)f2bf(src[j * HW_PIX]);
        }
        #pragma unroll
        for (int nt = 0; nt < 4; ++nt) {
            short8 bv = *(const short8*)(Wo + (o0 + nt * 16 + l16) * 256 + kbase);
            acc[nt] = __builtin_amdgcn_mfma_f32_16x16x32_bf16(av, bv, acc[nt], 0, 0, 0);
        }
    }

    // transpose through LDS, emit f32 [c][p]
    __shared__ short tile[128 * 40];
    #pragma unroll
    for (int nt = 0; nt < 4; ++nt) {
        const int o = o0 + nt * 16 + l16;
        const float sf = s[o], bf = b[o];
        #pragma unroll
        for (int i = 0; i < 4; ++i) {
            const float vl = acc[nt][i] * sf + bf;          // no ReLU
            tile[o * 40 + pg * 16 + g * 4 + i] = (short)f2bf(vl);
        }
    }
    __syncthreads();
    #pragma unroll
    for (int pass = 0; pass < 2; ++pass) {
        const int u = tid + pass * 256;        // 512 units of 8 elems
        const int o_r = u >> 2, q4 = u & 3;
        short8 val = *(const short8*)(&tile[o_r * 40 + q4 * 8]);
        const int doff = o_r * HW_PIX + p0b + q4 * 8;
        f32x4 lo, hi;
        #pragma unroll
        for (int j = 0; j < 4; ++j) {
            lo[j] = bf2f((unsigned short)val[j]);
            hi[j] = bf2f((unsigned short)val[4 + j]);
        }
        *(f32x4*)(out + doff)     = lo;
        *(f32x4*)(out + doff + 4) = hi;
    }
}

extern "C" void kernel_launch(void* const* d_in, const int* in_sizes, int n_in,
                              void* d_out, int out_size, void* d_ws, size_t ws_size,
                              hipStream_t stream)
{
    const float* x = (const float*)d_in[0];
    short* ws = (short*)d_ws;

    CvtArgs ca;
    ca.w[0] = (const float*)d_in[1];   // w_q1
    ca.w[1] = (const float*)d_in[4];   // w_q2
    ca.w[2] = (const float*)d_in[7];   // w_k1
    ca.w[3] = (const float*)d_in[10];  // w_k2
    ca.w[4] = (const float*)d_in[13];  // w_v
    ca.w[5] = (const float*)d_in[16];  // w_o
    ca.sb[0]  = (const float*)d_in[2];  ca.sb[1]  = (const float*)d_in[3];   // s_q1,b_q1
    ca.sb[2]  = (const float*)d_in[5];  ca.sb[3]  = (const float*)d_in[6];   // s_q2,b_q2
    ca.sb[4]  = (const float*)d_in[8];  ca.sb[5]  = (const float*)d_in[9];   // s_k1,b_k1
    ca.sb[6]  = (const float*)d_in[11]; ca.sb[7]  = (const float*)d_in[12];  // s_k2,b_k2
    ca.sb[8]  = (const float*)d_in[14]; ca.sb[9]  = (const float*)d_in[15];  // s_v,b_v
    ca.sb[10] = (const float*)d_in[17]; ca.sb[11] = (const float*)d_in[18];  // s_o,b_o

    cvt_k<<<dim3(62), dim3(256), 0, stream>>>(ca, ws);
    qkv_k<<<dim3(512), dim3(256), 0, stream>>>(x, ws);
    attn_k<<<dim3(512), dim3(256), 0, stream>>>(ws);
    final_k<<<dim3(512), dim3(256), 0, stream>>>(x, ws, (float*)d_out);
}